// Round 1
// baseline (196.582 us; speedup 1.0000x reference)
//
#include <hip/hip_runtime.h>
#include <math.h>
#include <stdint.h>

// CTC batch cost, keras.backend.ctc_batch_cost semantics.
// B=256, T=512, C=256 (blank=255), L=128, S=2L+1=257.
//
// Round 8: continuous-issue loaders. Round 7's loaders drained vmcnt(0) and
// hit __syncthreads (vmcnt(0) lgkmcnt(0) drain) every 32-row phase, so loads
// were in flight only ~50% of the time -> ~3.2 TB/s effective. New staging:
//   - global_load_lds dwordx4 (wave-uniform LDS base + lane*16 == our linear
//     row ring) -- no reg round-trip, no per-phase drain.
//   - 4-chunk ring (128 KB LDS), loaders run DEPTH=3 chunks ahead with
//     counted s_waitcnt vmcnt(10) (never 0 in steady state): 10-15 KB in
//     flight per loader wave x7 waves, HBM pipe never empties.
//   - raw s_barrier (not __syncthreads) so the barrier does not drain the
//     prefetch queue; asm memory clobbers pin LDS read/write ordering.
// Consumer: round-7 proven-exact DPP machinery unchanged (absmax 0.0),
// prefetch skew widened 2 -> 4 rows to cover LDS gather latency.

namespace {
constexpr int Bn = 256;
constexpr int Tn = 512;
constexpr int Cn = 256;
constexpr int Ln = 128;
constexpr int CH = 32;              // rows per chunk
constexpr int NCHUNK = Tn / CH;     // 16
constexpr int SLOTS = 128;          // LDS ring slots = 4 chunks (128 KB)
constexpr int DEPTH = 3;            // chunks prefetched ahead of consumer
constexpr float EPSf = 1e-7f;
constexpr float LN2f = 0.69314718055994530942f;
constexpr int   TGT  = 100;         // rescale target exponent
}

// counted vmem wait, N must be a literal
#define VMWAIT(N) asm volatile("s_waitcnt vmcnt(" #N ")" ::: "memory")

// raw barrier: no compiler-inserted vmcnt(0) drain (that is the point);
// memory clobbers stop LDS accesses migrating across it.
__device__ __forceinline__ void barrier_raw() {
    asm volatile("" ::: "memory");
    __builtin_amdgcn_s_barrier();
    asm volatile("" ::: "memory");
}

__device__ __forceinline__ float rdl63(float v) {
    return __int_as_float(__builtin_amdgcn_readlane(__float_as_int(v), 63));
}
// lane i <- lane i-1 (lane 0 <- 0): DPP wave_shr:1, bound_ctrl=1
__device__ __forceinline__ float dpp_shr1(float v) {
    return __int_as_float(__builtin_amdgcn_update_dpp(
        0, __float_as_int(v), 0x138, 0xF, 0xF, true));
}
template <int CTRL>
__device__ __forceinline__ float dpp_max(float m) {
    float o = __int_as_float(__builtin_amdgcn_update_dpp(
        0, __float_as_int(m), CTRL, 0xF, 0xF, true));   // invalid lanes -> 0
    return fmaxf(m, o);                                  // values >= 0, safe
}

__global__ __launch_bounds__(512, 1)
void ctc_fwd(const int* __restrict__ y_true,
             const float* __restrict__ y_pred,
             float* __restrict__ out)
{
    const int b    = blockIdx.x;
    const int tid  = (int)threadIdx.x;
    const int w    = tid >> 6;        // wave id 0..7
    const int lane = tid & 63;

    __shared__ __align__(16) float lds[SLOTS * Cn];   // 128 KB row ring

    const float* gbase = y_pred + (size_t)b * Tn * Cn;

    // ---- loader: issue chunk ch's rows as global_load_lds (no drain) ------
    // LDS dst is wave-uniform (row slot base); HW scatters lane*16B -> the
    // linear row layout the consumer expects. Duplicate row-31 issues from
    // the clamp write identical bytes (benign; L2 dedups the refetch).
    auto issue_chunk = [&](int ch) {
        #pragma unroll
        for (int k = 0; k < 5; ++k) {
            int rl = (w - 1) + 7 * k;              // 7 loader waves
            rl = rl > CH - 1 ? CH - 1 : rl;
            const int t = ch * CH + rl;
            const float* gp = gbase + (size_t)t * Cn + lane * 4;   // lane*16B
            float* lp = &lds[(t & (SLOTS - 1)) * Cn];              // uniform
            __builtin_amdgcn_global_load_lds(
                (const __attribute__((address_space(1))) void*)gp,
                (__attribute__((address_space(3))) void*)lp,
                16, 0, 0);
        }
    };

    // ---- consumer state (wave 0 only; keeps loader vmcnt streams clean) ---
    int l0 = 0, l1 = 0;
    float sk1 = 0.0f, sk3 = 0.0f;
    float a0 = 0.0f, a1 = 0.0f, a2 = 0.0f, a3 = 0.0f, a4 = 0.0f;
    int Eacc = -100;
    if (w == 0) {
        const int* yt = y_true + b * Ln;
        l0 = yt[2 * lane];                          // state 4i+1 label
        l1 = yt[2 * lane + 1];                      // state 4i+3 label
        const int lm = (lane > 0) ? yt[2 * lane - 1] : -1;
        sk1 = (lane > 0 && l0 != lm) ? 1.0f : 0.0f;
        sk3 = (l1 != l0) ? 1.0f : 0.0f;
        a0 = (lane == 0) ? 0x1p100f : 0.0f;         // true_alpha = stored*2^Eacc
    }

    auto step = [&](float rb, float r0, float r1) {
        const float n = dpp_shr1(a3);        // alpha[4i-1], VALU not DS
        const float Pb = rb + EPSf;
        const float P0 = r0 + EPSf;
        const float P1 = r1 + EPSf;
        const float na0 = (a0 + n) * Pb;
        const float na1 = fmaf(sk1, n,  a1 + a0) * P0;
        const float na2 = (a2 + a1) * Pb;
        const float na3 = fmaf(sk3, a1, a3 + a2) * P1;
        const float na4 = (a4 + a3) * Pb;
        a0 = na0; a1 = na1; a2 = na2; a3 = na3; a4 = na4;
    };

    auto rescale = [&]() {
        float m = fmaxf(fmaxf(fmaxf(a0, a1), fmaxf(a2, a3)), a4);
        m = dpp_max<0x111>(m);               // row_shr:1
        m = dpp_max<0x112>(m);               // row_shr:2
        m = dpp_max<0x114>(m);               // row_shr:4
        m = dpp_max<0x118>(m);               // row_shr:8
        m = dpp_max<0x142>(m);               // row_bcast:15
        m = dpp_max<0x143>(m);               // row_bcast:31
        m = rdl63(m);                        // wave-uniform max
        int e;
        (void)frexpf(m, &e);
        const int shift = TGT - e;
        a0 = ldexpf(a0, shift);
        a1 = ldexpf(a1, shift);
        a2 = ldexpf(a2, shift);
        a3 = ldexpf(a3, shift);
        a4 = ldexpf(a4, shift);
        Eacc -= shift;
    };

    // ---- consumer: 32 steps of chunk c from the ring, skew-4 pipeline -----
    auto consume_chunk = [&](int c) {
        const int t0 = c * CH;
        float rb0, r00, r10, rb1, r01, r11;
        float rb2, r02, r12, rb3, r03, r13;
        int s = ((t0 + 0) & (SLOTS - 1)) * Cn;
        rb0 = lds[s + (Cn - 1)]; r00 = lds[s + l0]; r10 = lds[s + l1];
        s = ((t0 + 1) & (SLOTS - 1)) * Cn;
        rb1 = lds[s + (Cn - 1)]; r01 = lds[s + l0]; r11 = lds[s + l1];
        s = ((t0 + 2) & (SLOTS - 1)) * Cn;
        rb2 = lds[s + (Cn - 1)]; r02 = lds[s + l0]; r12 = lds[s + l1];
        s = ((t0 + 3) & (SLOTS - 1)) * Cn;
        rb3 = lds[s + (Cn - 1)]; r03 = lds[s + l0]; r13 = lds[s + l1];
        #pragma unroll
        for (int j = 0; j < CH; ++j) {
            float rbn = 0.0f, r0n = 0.0f, r1n = 0.0f;
            if (j < CH - 4) {                // read row t0+j+4 (same chunk)
                const int ss = ((t0 + j + 4) & (SLOTS - 1)) * Cn;
                rbn = lds[ss + (Cn - 1)];
                r0n = lds[ss + l0];
                r1n = lds[ss + l1];
            }
            step(rb0, r00, r10);             // step t0+j
            rb0 = rb1; r00 = r01; r10 = r11;
            rb1 = rb2; r01 = r02; r11 = r12;
            rb2 = rb3; r02 = r03; r12 = r13;
            rb3 = rbn; r03 = r0n; r13 = r1n;
            if ((j & 15) == 15) rescale();   // every 16 steps (unchanged)
        }
    };

    // ---- pipeline ---------------------------------------------------------
    // Invariant: at the start of phase c, chunks <= c are complete in LDS.
    // Loader wave, phase c: issue chunk c+3, then wait until only the loads
    // of chunks >= c+2 are outstanding (5 loads/chunk/wave) -> chunk c+1 is
    // guaranteed before the barrier that opens phase c+1.
    if (w > 0) {
        issue_chunk(0);
        issue_chunk(1);
        issue_chunk(2);
        VMWAIT(10);                          // chunk 0 landed; 1,2 in flight
    }
    barrier_raw();

    for (int c = 0; c < NCHUNK; ++c) {
        if (w > 0) {
            if (c + DEPTH < NCHUNK) issue_chunk(c + DEPTH);
            if (c <= NCHUNK - 4)      VMWAIT(10);  // chunks c+2,c+3 in flight
            else if (c == NCHUNK - 3) VMWAIT(5);   // chunk 15 in flight
            else                      VMWAIT(0);   // epilogue drain
        } else {
            consume_chunk(c);
        }
        barrier_raw();
    }

    // loss = -ln(alpha[S-1] + alpha[S-2]); states 255,256 = lane63 a3,a4
    if (w == 0 && lane == 63) {
        const float sfin = a3 + a4;
        out[b] = -LN2f * (log2f(sfin) + (float)Eacc);
    }
}

extern "C" void kernel_launch(void* const* d_in, const int* in_sizes, int n_in,
                              void* d_out, int out_size, void* d_ws, size_t ws_size,
                              hipStream_t stream) {
    const int*   y_true = (const int*)  d_in[0];   // [256,128] int32
    const float* y_pred = (const float*)d_in[1];   // [256,512,256] fp32
    float* out = (float*)d_out;                    // [256,1] fp32
    (void)in_sizes; (void)n_in; (void)out_size; (void)d_ws; (void)ws_size;
    ctc_fwd<<<dim3(Bn), dim3(512), 0, stream>>>(y_true, y_pred, out);
}

// Round 2
// 195.869 us; speedup vs baseline: 1.0036x; 1.0036x over previous
//
#include <hip/hip_runtime.h>
#include <math.h>
#include <stdint.h>

// CTC batch cost, keras.backend.ctc_batch_cost semantics.
// B=256, T=512, C=256 (blank=255), L=128, S=2L+1=257.
//
// Round 9: double the loader wave count. Evidence: r7 (vmcnt(0) drain per
// phase) and r8 (counted vmcnt, depth-3) give IDENTICAL kernel time (~41us)
// -> loader limit is not outstanding-op depth. Round-6 measurement: ~14
// 64B miss-lines in flight per wave; one global_load_lds_dwordx4 spans 16
// lines, so ONE instruction saturates a wave's miss budget and deeper
// queues add nothing. 7 waves x 14 lines x 64B / ~1200cy = ~5.2 B/cy/CU =
// exactly 512KB/41us. Only MORE WAVES raise line concurrency.
//   1024 threads = 16 waves: wave 0 consumer (r6 proven-exact DPP
//   machinery, unchanged bit-for-bit), waves 1-15 loaders (2-3 rows per
//   chunk each, no duplicate loads). Counted waits: vmcnt(4) steady state
//   (covers both 2-load and 3-load waves), vmcnt(2)/vmcnt(0) epilogue.
// Ring (4 chunks, 128KB), raw barriers, depth-3 prefetch: as round 8.

namespace {
constexpr int Bn = 256;
constexpr int Tn = 512;
constexpr int Cn = 256;
constexpr int Ln = 128;
constexpr int CH = 32;              // rows per chunk
constexpr int NCHUNK = Tn / CH;     // 16
constexpr int SLOTS = 128;          // LDS ring slots = 4 chunks (128 KB)
constexpr int DEPTH = 3;            // chunks prefetched ahead of consumer
constexpr int NLOAD = 15;           // loader waves
constexpr float EPSf = 1e-7f;
constexpr float LN2f = 0.69314718055994530942f;
constexpr int   TGT  = 100;         // rescale target exponent
}

// counted vmem wait, N must be a literal
#define VMWAIT(N) asm volatile("s_waitcnt vmcnt(" #N ")" ::: "memory")

// raw barrier: no compiler-inserted vmcnt(0) drain; memory clobbers stop
// LDS accesses migrating across it.
__device__ __forceinline__ void barrier_raw() {
    asm volatile("" ::: "memory");
    __builtin_amdgcn_s_barrier();
    asm volatile("" ::: "memory");
}

__device__ __forceinline__ float rdl63(float v) {
    return __int_as_float(__builtin_amdgcn_readlane(__float_as_int(v), 63));
}
// lane i <- lane i-1 (lane 0 <- 0): DPP wave_shr:1, bound_ctrl=1
__device__ __forceinline__ float dpp_shr1(float v) {
    return __int_as_float(__builtin_amdgcn_update_dpp(
        0, __float_as_int(v), 0x138, 0xF, 0xF, true));
}
template <int CTRL>
__device__ __forceinline__ float dpp_max(float m) {
    float o = __int_as_float(__builtin_amdgcn_update_dpp(
        0, __float_as_int(m), CTRL, 0xF, 0xF, true));   // invalid lanes -> 0
    return fmaxf(m, o);                                  // values >= 0, safe
}

__global__ __launch_bounds__(1024, 1)
void ctc_fwd(const int* __restrict__ y_true,
             const float* __restrict__ y_pred,
             float* __restrict__ out)
{
    const int b    = blockIdx.x;
    const int tid  = (int)threadIdx.x;
    const int w    = tid >> 6;        // wave id 0..15
    const int lane = tid & 63;

    __shared__ __align__(16) float lds[SLOTS * Cn];   // 128 KB row ring

    const float* gbase = y_pred + (size_t)b * Tn * Cn;

    // ---- loader: issue chunk ch's rows as global_load_lds (no drain) ------
    // Row striping over 15 loader waves: rl = (w-1) + 15*k, k = 0..2.
    // k=0 -> rows 0..14, k=1 -> 15..29, k=2 -> rows 30,31 (waves 1,2 only).
    // Every row issued exactly once; waves have 2 or 3 loads per chunk.
    auto issue_chunk = [&](int ch) {
        #pragma unroll
        for (int k = 0; k < 3; ++k) {
            const int rl = (w - 1) + NLOAD * k;
            if (rl < CH) {
                const int t = ch * CH + rl;
                const float* gp = gbase + (size_t)t * Cn + lane * 4;  // lane*16B
                float* lp = &lds[(t & (SLOTS - 1)) * Cn];             // uniform
                __builtin_amdgcn_global_load_lds(
                    (const __attribute__((address_space(1))) void*)gp,
                    (__attribute__((address_space(3))) void*)lp,
                    16, 0, 0);
            }
        }
    };

    // ---- consumer state (wave 0 only) -------------------------------------
    int l0 = 0, l1 = 0;
    float sk1 = 0.0f, sk3 = 0.0f;
    float a0 = 0.0f, a1 = 0.0f, a2 = 0.0f, a3 = 0.0f, a4 = 0.0f;
    int Eacc = -100;
    if (w == 0) {
        const int* yt = y_true + b * Ln;
        l0 = yt[2 * lane];                          // state 4i+1 label
        l1 = yt[2 * lane + 1];                      // state 4i+3 label
        const int lm = (lane > 0) ? yt[2 * lane - 1] : -1;
        sk1 = (lane > 0 && l0 != lm) ? 1.0f : 0.0f;
        sk3 = (l1 != l0) ? 1.0f : 0.0f;
        a0 = (lane == 0) ? 0x1p100f : 0.0f;         // true_alpha = stored*2^Eacc
    }

    auto step = [&](float rb, float r0, float r1) {
        const float n = dpp_shr1(a3);        // alpha[4i-1], VALU not DS
        const float Pb = rb + EPSf;
        const float P0 = r0 + EPSf;
        const float P1 = r1 + EPSf;
        const float na0 = (a0 + n) * Pb;
        const float na1 = fmaf(sk1, n,  a1 + a0) * P0;
        const float na2 = (a2 + a1) * Pb;
        const float na3 = fmaf(sk3, a1, a3 + a2) * P1;
        const float na4 = (a4 + a3) * Pb;
        a0 = na0; a1 = na1; a2 = na2; a3 = na3; a4 = na4;
    };

    auto rescale = [&]() {
        float m = fmaxf(fmaxf(fmaxf(a0, a1), fmaxf(a2, a3)), a4);
        m = dpp_max<0x111>(m);               // row_shr:1
        m = dpp_max<0x112>(m);               // row_shr:2
        m = dpp_max<0x114>(m);               // row_shr:4
        m = dpp_max<0x118>(m);               // row_shr:8
        m = dpp_max<0x142>(m);               // row_bcast:15
        m = dpp_max<0x143>(m);               // row_bcast:31
        m = rdl63(m);                        // wave-uniform max
        int e;
        (void)frexpf(m, &e);
        const int shift = TGT - e;
        a0 = ldexpf(a0, shift);
        a1 = ldexpf(a1, shift);
        a2 = ldexpf(a2, shift);
        a3 = ldexpf(a3, shift);
        a4 = ldexpf(a4, shift);
        Eacc -= shift;
    };

    // ---- consumer: 32 steps of chunk c from the ring, skew-4 pipeline -----
    auto consume_chunk = [&](int c) {
        const int t0 = c * CH;
        float rb0, r00, r10, rb1, r01, r11;
        float rb2, r02, r12, rb3, r03, r13;
        int s = ((t0 + 0) & (SLOTS - 1)) * Cn;
        rb0 = lds[s + (Cn - 1)]; r00 = lds[s + l0]; r10 = lds[s + l1];
        s = ((t0 + 1) & (SLOTS - 1)) * Cn;
        rb1 = lds[s + (Cn - 1)]; r01 = lds[s + l0]; r11 = lds[s + l1];
        s = ((t0 + 2) & (SLOTS - 1)) * Cn;
        rb2 = lds[s + (Cn - 1)]; r02 = lds[s + l0]; r12 = lds[s + l1];
        s = ((t0 + 3) & (SLOTS - 1)) * Cn;
        rb3 = lds[s + (Cn - 1)]; r03 = lds[s + l0]; r13 = lds[s + l1];
        #pragma unroll
        for (int j = 0; j < CH; ++j) {
            float rbn = 0.0f, r0n = 0.0f, r1n = 0.0f;
            if (j < CH - 4) {                // read row t0+j+4 (same chunk)
                const int ss = ((t0 + j + 4) & (SLOTS - 1)) * Cn;
                rbn = lds[ss + (Cn - 1)];
                r0n = lds[ss + l0];
                r1n = lds[ss + l1];
            }
            step(rb0, r00, r10);             // step t0+j
            rb0 = rb1; r00 = r01; r10 = r11;
            rb1 = rb2; r01 = r02; r11 = r12;
            rb2 = rb3; r02 = r03; r12 = r13;
            rb3 = rbn; r03 = r0n; r13 = r1n;
            if ((j & 15) == 15) rescale();   // every 16 steps (unchanged)
        }
    };

    // ---- pipeline ---------------------------------------------------------
    // Invariant: at the start of phase c, chunks <= c are complete in LDS.
    // Waits must guarantee the wave's own loads of chunk c+1 are retired
    // before the barrier ending phase c. Per-wave loads/chunk n_w in {2,3}:
    //   steady state outstanding = 3*n_w (chunks c+1..c+3); VMWAIT(4)
    //   drains >= n_w oldest for both n_w=2 (6->4) and n_w=3 (9->4).
    if (w > 0) {
        issue_chunk(0);
        issue_chunk(1);
        issue_chunk(2);
        VMWAIT(4);                           // chunk 0 landed; 1,2 in flight
    }
    barrier_raw();

    for (int c = 0; c < NCHUNK; ++c) {
        if (w > 0) {
            if (c + DEPTH < NCHUNK) issue_chunk(c + DEPTH);
            if (c <= NCHUNK - 4)      VMWAIT(4);  // chunk c+1 done, rest fly
            else if (c == NCHUNK - 3) VMWAIT(2);  // chunk 14 done, 15 flies
            else                      VMWAIT(0);  // epilogue drain
        } else {
            consume_chunk(c);
        }
        barrier_raw();
    }

    // loss = -ln(alpha[S-1] + alpha[S-2]); states 255,256 = lane63 a3,a4
    if (w == 0 && lane == 63) {
        const float sfin = a3 + a4;
        out[b] = -LN2f * (log2f(sfin) + (float)Eacc);
    }
}

extern "C" void kernel_launch(void* const* d_in, const int* in_sizes, int n_in,
                              void* d_out, int out_size, void* d_ws, size_t ws_size,
                              hipStream_t stream) {
    const int*   y_true = (const int*)  d_in[0];   // [256,128] int32
    const float* y_pred = (const float*)d_in[1];   // [256,512,256] fp32
    float* out = (float*)d_out;                    // [256,1] fp32
    (void)in_sizes; (void)n_in; (void)out_size; (void)d_ws; (void)ws_size;
    ctc_fwd<<<dim3(Bn), dim3(1024), 0, stream>>>(y_true, y_pred, out);
}